// Round 14
// baseline (177.085 us; speedup 1.0000x reference)
//
#include <hip/hip_runtime.h>
#include <hip/hip_bf16.h>
#include <math.h>

#define NTOK 2048
#define HID 2048
#define NEXP 8
#define FINT 768
#define TOPK 2

typedef __attribute__((ext_vector_type(8))) short bf16x8;
typedef __attribute__((ext_vector_type(4))) float f32x4;

static __device__ __forceinline__ unsigned short f2bf(float f) {
    union { float f; unsigned u; } v; v.f = f;
    unsigned r = v.u + 0x7fffu + ((v.u >> 16) & 1u);
    return (unsigned short)(r >> 16);
}

static __device__ __forceinline__ void gl16(const void* g, void* l) {
    __builtin_amdgcn_global_load_lds(
        (const __attribute__((address_space(1))) unsigned int*)g,
        (__attribute__((address_space(3))) unsigned int*)(uintptr_t)l,
        16, 0, 0);
}

// ---------------- workspace layout (bytes) ----------------
// 0       : topk_idx  int[4096]
// 16384   : topk_w    f32[4096]
// 32768   : counts    int[8]
// 32800   : offsets   int[8]
// 33024   : row_token int[4096]
// 49408   : row_w     f32[4096]
// 65792   : elist_t   int[8*2048]
// 131328  : elist_w   f32[8*2048]
// 196864  : x_bf16    [2048][2048]        8388608
// 8585472 : wg_t      [8][768][2048] bf16 25165824
// 33751296: wu_t      [8][768][2048] bf16 25165824
// 58917120: wd_t      [8][2048][768] bf16 25165824
// 84082944: h_buf     [4224][768]    bf16 6488064   -> end 90571008

struct TP { const float* s; unsigned short* d; int R, C, r0, c0; };

static __device__ __forceinline__ TP tp_decode(
        int t,
        const float* wg, const float* wu, const float* wd,
        unsigned short* wgt, unsigned short* wut, unsigned short* wdt) {
    TP p;
    if (t < 6144) {
        int e = t / 768, sub = t % 768;
        if (sub < 384) { p.s = wg; p.d = wgt; }
        else           { p.s = wu; p.d = wut; sub -= 384; }
        p.R = HID; p.C = FINT;
        p.r0 = (sub / 12) * 64; p.c0 = (sub % 12) * 64;   // [2048][768]: 32x12
        p.s += (size_t)e * HID * FINT; p.d += (size_t)e * HID * FINT;
    } else {
        t -= 6144;
        int e = t / 384, sub = t % 384;
        p.s = wd + (size_t)e * FINT * HID; p.d = wdt + (size_t)e * FINT * HID;
        p.R = FINT; p.C = HID;
        p.r0 = (sub / 32) * 64; p.c0 = (sub % 32) * 64;   // [768][2048]: 12x32
    }
    return p;
}

// ---------------- K1: router + x-cvt + out-zero  UNION  pipelined transposes
// blocks [0,512): router (4 tokens each; zeroes out rows; writes xb)
// blocks [512, 2816): 4 consecutive 64x64 transpose tiles each, dbuf-pipelined
__global__ __launch_bounds__(256) void k1_all(
        const float* __restrict__ x,
        const float* __restrict__ gw,
        const float* __restrict__ wg, const float* __restrict__ wu,
        const float* __restrict__ wd,
        float* __restrict__ out,
        float* __restrict__ logits_out,
        int* __restrict__ topk_idx,
        float* __restrict__ topk_w,
        unsigned short* __restrict__ xb,
        unsigned short* __restrict__ wgt, unsigned short* __restrict__ wut,
        unsigned short* __restrict__ wdt) {
    __shared__ __align__(16) float tile2[2][64 * 64];   // 32 KB
    int bid = blockIdx.x;
    if (bid < 512) {
        int w = threadIdx.x >> 6, l = threadIdx.x & 63;
        int t = bid * 4 + w;
        const float4* xr = (const float4*)(x + (size_t)t * HID);
        unsigned short* xbr = xb + (size_t)t * HID;
        float4 v[8];
        #pragma unroll
        for (int i = 0; i < 8; ++i) v[i] = xr[i * 64 + l];
        #pragma unroll
        for (int i = 0; i < 8; ++i)
            *(ushort4*)&xbr[(i * 64 + l) * 4] =
                make_ushort4(f2bf(v[i].x), f2bf(v[i].y), f2bf(v[i].z), f2bf(v[i].w));
        {
            float4 z = make_float4(0.f, 0.f, 0.f, 0.f);
            float4* orow = (float4*)(out + (size_t)t * HID);
            #pragma unroll
            for (int i = 0; i < 8; ++i) orow[i * 64 + l] = z;
        }
        float acc[NEXP];
        #pragma unroll
        for (int e = 0; e < NEXP; ++e) {
            const float4* gr = (const float4*)(gw + (size_t)e * HID);
            float a = 0.f;
            #pragma unroll
            for (int i = 0; i < 8; ++i) {
                float4 g = gr[i * 64 + l];
                a += v[i].x * g.x + v[i].y * g.y + v[i].z * g.z + v[i].w * g.w;
            }
            acc[e] = a;
        }
        #pragma unroll
        for (int off = 32; off > 0; off >>= 1)
            #pragma unroll
            for (int e = 0; e < NEXP; ++e) acc[e] += __shfl_xor(acc[e], off);
        if (l == 0) {
            float m = -1e30f;
            #pragma unroll
            for (int i = 0; i < NEXP; ++i) m = fmaxf(m, acc[i]);
            float p[NEXP];
            #pragma unroll
            for (int i = 0; i < NEXP; ++i) p[i] = expf(acc[i] - m);
            int i0 = 0;
            #pragma unroll
            for (int i = 1; i < NEXP; ++i) if (p[i] > p[i0]) i0 = i;
            int i1 = (i0 == 0) ? 1 : 0;
            #pragma unroll
            for (int i = 0; i < NEXP; ++i) if (i != i0 && p[i] > p[i1]) i1 = i;
            float w0 = p[i0], w1 = p[i1], sw = w0 + w1;
            topk_idx[t * 2 + 0] = i0;
            topk_idx[t * 2 + 1] = i1;
            topk_w[t * 2 + 0] = w0 / sw;
            topk_w[t * 2 + 1] = w1 / sw;
            #pragma unroll
            for (int i = 0; i < NEXP; ++i) logits_out[(size_t)t * NEXP + i] = acc[i];
        }
    } else {
        int g = (bid - 512) * 4;          // first of 4 consecutive tiles
        int tid = threadIdx.x;
        int rbase = tid >> 4, ch = tid & 15;
        int pswz = (ch ^ rbase) * 4;      // swizzled chunk (row&15 == rbase)
        int r16 = (tid & 15) * 4, cg = tid >> 4;

        TP cur = tp_decode(g, wg, wu, wd, wgt, wut, wdt);
        float4 ld[4];
        #pragma unroll
        for (int i = 0; i < 4; ++i)
            ld[i] = *(const float4*)&cur.s[(size_t)(cur.r0 + i * 16 + rbase) * cur.C
                                           + cur.c0 + ch * 4];
        #pragma unroll
        for (int i = 0; i < 4; ++i)
            *(float4*)&tile2[0][(i * 16 + rbase) * 64 + pswz] = ld[i];
        __syncthreads();

        for (int it = 0; it < 4; ++it) {
            int cb = it & 1;
            TP nxt;
            if (it < 3) {
                nxt = tp_decode(g + it + 1, wg, wu, wd, wgt, wut, wdt);
                #pragma unroll
                for (int i = 0; i < 4; ++i)
                    ld[i] = *(const float4*)&nxt.s[(size_t)(nxt.r0 + i * 16 + rbase) * nxt.C
                                                   + nxt.c0 + ch * 4];
            }
            // phase 2: column gather from tile2[cb], register transpose, store
            float4 v[4];
            #pragma unroll
            for (int j = 0; j < 4; ++j) {
                int row = r16 + j;
                int p = cg ^ (row & 15);
                v[j] = *(const float4*)&tile2[cb][row * 64 + p * 4];
            }
            #pragma unroll
            for (int i2 = 0; i2 < 4; ++i2) {
                float c0v = (i2 == 0) ? v[0].x : (i2 == 1) ? v[0].y : (i2 == 2) ? v[0].z : v[0].w;
                float c1v = (i2 == 0) ? v[1].x : (i2 == 1) ? v[1].y : (i2 == 2) ? v[1].z : v[1].w;
                float c2v = (i2 == 0) ? v[2].x : (i2 == 1) ? v[2].y : (i2 == 2) ? v[2].z : v[2].w;
                float c3v = (i2 == 0) ? v[3].x : (i2 == 1) ? v[3].y : (i2 == 2) ? v[3].z : v[3].w;
                ushort4 o = make_ushort4(f2bf(c0v), f2bf(c1v), f2bf(c2v), f2bf(c3v));
                *(uint2*)&cur.d[(size_t)(cur.c0 + cg * 4 + i2) * cur.R + cur.r0 + r16] =
                    *(const uint2*)&o;
            }
            if (it < 3) {
                #pragma unroll
                for (int i = 0; i < 4; ++i)
                    *(float4*)&tile2[cb ^ 1][(i * 16 + rbase) * 64 + pswz] = ld[i];
                cur = nxt;
            }
            __syncthreads();
        }
    }
}

__global__ void moe_build_kernel(const int* __restrict__ topk_idx,
                                 const float* __restrict__ topk_w,
                                 int* __restrict__ counts,
                                 int* __restrict__ offsets,
                                 int* __restrict__ elist_t,
                                 float* __restrict__ elist_w,
                                 int* __restrict__ row_token,
                                 float* __restrict__ row_w) {
    __shared__ int scnt[NEXP];
    __shared__ int soff[NEXP];
    int tid = threadIdx.x; // 1024
    if (tid < NEXP) scnt[tid] = 0;
    __syncthreads();
    for (int t = tid; t < NTOK; t += 1024) {
        #pragma unroll
        for (int k = 0; k < TOPK; ++k) {
            int e = topk_idx[t * 2 + k];
            float w = topk_w[t * 2 + k];
            int slot = atomicAdd(&scnt[e], 1);
            elist_t[e * NTOK + slot] = t;
            elist_w[e * NTOK + slot] = w;
        }
    }
    __syncthreads();
    if (tid == 0) {
        int o = 0;
        for (int e = 0; e < NEXP; ++e) {
            soff[e] = o; offsets[e] = o; counts[e] = scnt[e]; o += scnt[e];
        }
    }
    __syncthreads();
    for (int e = 0; e < NEXP; ++e) {
        int c = scnt[e], o = soff[e];
        for (int s = tid; s < c; s += 1024) {
            row_token[o + s] = elist_t[e * NTOK + s];
            row_w[o + s]     = elist_w[e * NTOK + s];
        }
    }
}

// ---------------- MFMA stage A: h = silu(x*Wg) * (x*Wu) ----------------
// 64x64 tile (g+u share A), BK=64, 4 waves 2x2, double-buffered prefetch.
__global__ __launch_bounds__(256) void moe_stage_a_mfma(
        const unsigned short* __restrict__ xb,    // [2048][2048]
        const unsigned short* __restrict__ wgt,   // [8][768][2048]
        const unsigned short* __restrict__ wut,   // [8][768][2048]
        const int* __restrict__ counts,
        const int* __restrict__ offsets,
        const int* __restrict__ row_token,
        unsigned short* __restrict__ h_buf) {     // [4224][768]
    int e = blockIdx.x, mt = blockIdx.y, nt = blockIdx.z;
    int count = counts[e];
    int m0 = mt * 64;
    if (m0 >= count) return;
    int off = offsets[e];
    int n0 = nt * 64;
    int mcnt = min(64, count - m0);
    int tid = threadIdx.x;

    __shared__ __align__(16) unsigned short As[2][64 * 64];
    __shared__ __align__(16) unsigned short Bg[2][64 * 64];
    __shared__ __align__(16) unsigned short Bu[2][64 * 64];
    __shared__ int toks[64];
    if (tid < 64) toks[tid] = row_token[off + m0 + min(tid, mcnt - 1)];
    __syncthreads();

    int w = tid >> 6, l = tid & 63;
    int wr = w >> 1, wc = w & 1;
    int lr = l & 15, lh = l >> 4;
    int rA = w * 8 + (l >> 3);    // staging row (0..31), +32 per issue
    int cA = l & 7;               // 16B chunk within 128B row

    const unsigned short* wgE = wgt + (size_t)e * FINT * HID + (size_t)n0 * HID;
    const unsigned short* wuE = wut + (size_t)e * FINT * HID + (size_t)n0 * HID;

    f32x4 gacc[2][2] = {};
    f32x4 uacc[2][2] = {};

    auto STAGE = [&](int buf, int k0) {
        #pragma unroll
        for (int i = 0; i < 2; ++i) {
            int row = 32 * i + rA;
            int sc = (cA ^ (row & 7)) << 3;      // pre-swizzled source offset
            size_t db = (size_t)(32 * i + w * 8) * 128;
            gl16(xb + (size_t)toks[row] * HID + k0 + sc, (char*)&As[buf][0] + db);
            gl16(wgE + (size_t)row * HID + k0 + sc,      (char*)&Bg[buf][0] + db);
            gl16(wuE + (size_t)row * HID + k0 + sc,      (char*)&Bu[buf][0] + db);
        }
    };

    auto COMPUTE = [&](int buf) {
        #pragma unroll
        for (int ks = 0; ks < 2; ++ks) {
            bf16x8 af[2], bg[2], bu[2];
            #pragma unroll
            for (int mi = 0; mi < 2; ++mi) {
                int row = wr * 32 + mi * 16 + lr;
                int byte = row * 128 + ((ks * 64 + lh * 16) ^ ((row & 7) << 4));
                af[mi] = *(const bf16x8*)((const char*)&As[buf][0] + byte);
            }
            #pragma unroll
            for (int ni = 0; ni < 2; ++ni) {
                int row = wc * 32 + ni * 16 + lr;
                int byte = row * 128 + ((ks * 64 + lh * 16) ^ ((row & 7) << 4));
                bg[ni] = *(const bf16x8*)((const char*)&Bg[buf][0] + byte);
                bu[ni] = *(const bf16x8*)((const char*)&Bu[buf][0] + byte);
            }
            #pragma unroll
            for (int mi = 0; mi < 2; ++mi)
                #pragma unroll
                for (int ni = 0; ni < 2; ++ni) {
                    gacc[mi][ni] = __builtin_amdgcn_mfma_f32_16x16x32_bf16(af[mi], bg[ni], gacc[mi][ni], 0, 0, 0);
                    uacc[mi][ni] = __builtin_amdgcn_mfma_f32_16x16x32_bf16(af[mi], bu[ni], uacc[mi][ni], 0, 0, 0);
                }
        }
    };

    STAGE(0, 0);
    __syncthreads();                   // drain buf0
    for (int t = 0; t < HID / 64; ++t) {
        int cur = t & 1;
        if (t + 1 < HID / 64) STAGE(cur ^ 1, (t + 1) * 64);  // prefetch next
        COMPUTE(cur);                  // overlap with in-flight loads
        __syncthreads();               // drain next-tile loads + guard reuse
    }

    #pragma unroll
    for (int mi = 0; mi < 2; ++mi)
        #pragma unroll
        for (int ni = 0; ni < 2; ++ni)
            #pragma unroll
            for (int j = 0; j < 4; ++j) {
                int row = wr * 32 + mi * 16 + lh * 4 + j;
                if (row < mcnt) {
                    int col = wc * 32 + ni * 16 + lr;
                    float g = gacc[mi][ni][j], u = uacc[mi][ni][j];
                    float hv = g / (1.f + expf(-g)) * u;
                    h_buf[(size_t)(off + m0 + row) * FINT + n0 + col] = f2bf(hv);
                }
            }
}

// ---------------- MFMA stage B: out[tok] += w * (h * Wd) ----------------
__global__ __launch_bounds__(256) void moe_stage_b_mfma(
        const unsigned short* __restrict__ h_buf, // [4224][768]
        const unsigned short* __restrict__ wdt,   // [8][2048][768]
        const int* __restrict__ counts,
        const int* __restrict__ offsets,
        const int* __restrict__ row_token,
        const float* __restrict__ row_w,
        float* __restrict__ out) {
    int e = blockIdx.x, mt = blockIdx.y, nt = blockIdx.z;
    int count = counts[e];
    int m0 = mt * 128;
    if (m0 >= count) return;
    int off = offsets[e];
    int n0 = nt * 128;
    int mcnt = min(128, count - m0);
    int tid = threadIdx.x;

    __shared__ __align__(16) unsigned short As[2][128 * 64];  // 32 KB
    __shared__ __align__(16) unsigned short Bs[2][128 * 64];  // 32 KB
    __shared__ int toks[128];
    __shared__ float rws[128];
    if (tid < 128) {
        int mm = min(tid, mcnt - 1);
        toks[tid] = row_token[off + m0 + mm];
        rws[tid] = row_w[off + m0 + mm];
    }
    __syncthreads();

    int w = tid >> 6, l = tid & 63;
    int wr = w >> 1, wc = w & 1;
    int lr = l & 15, lh = l >> 4;
    int wbase = (tid & 192) * 16;   // wave-uniform byte base within 4KB slab

    const unsigned short* hb = h_buf + (size_t)(off + m0) * FINT;
    const unsigned short* wdE = wdt + (size_t)e * HID * FINT + (size_t)n0 * FINT;

    f32x4 acc[4][4] = {};

    auto STAGE = [&](int buf, int k0) {
        #pragma unroll
        for (int i = 0; i < 4; ++i) {
            int s = i * 256 + tid;
            int row = s >> 3, c = s & 7;
            int sc = (c ^ (row & 7)) << 3;
            gl16(hb + (size_t)row * FINT + k0 + sc,  (char*)&As[buf][0] + i * 4096 + wbase);
            gl16(wdE + (size_t)row * FINT + k0 + sc, (char*)&Bs[buf][0] + i * 4096 + wbase);
        }
    };

    auto COMPUTE = [&](int buf) {
        #pragma unroll
        for (int ks = 0; ks < 2; ++ks) {
            bf16x8 af[4], bf[4];
            #pragma unroll
            for (int mi = 0; mi < 4; ++mi) {
                int row = wr * 64 + mi * 16 + lr;
                int byte = row * 128 + ((ks * 64 + lh * 16) ^ ((row & 7) << 4));
                af[mi] = *(const bf16x8*)((const char*)&As[buf][0] + byte);
            }
            #pragma unroll
            for (int ni = 0; ni < 4; ++ni) {
                int row = wc * 64 + ni * 16 + lr;
                int byte = row * 128 + ((ks * 64 + lh * 16) ^ ((row & 7) << 4));
                bf[ni] = *(const bf16x8*)((const char*)&Bs[buf][0] + byte);
            }
            #pragma unroll
            for (int mi = 0; mi < 4; ++mi)
                #pragma unroll
                for (int ni = 0; ni < 4; ++ni)
                    acc[mi][ni] = __builtin_amdgcn_mfma_f32_16x16x32_bf16(af[mi], bf[ni], acc[mi][ni], 0, 0, 0);
        }
    };

    STAGE(0, 0);
    __syncthreads();
    for (int t = 0; t < FINT / 64; ++t) {
        int cur = t & 1;
        if (t + 1 < FINT / 64) STAGE(cur ^ 1, (t + 1) * 64);
        COMPUTE(cur);
        __syncthreads();
    }

    #pragma unroll
    for (int mi = 0; mi < 4; ++mi)
        #pragma unroll
        for (int ni = 0; ni < 4; ++ni)
            #pragma unroll
            for (int j = 0; j < 4; ++j) {
                int row = wr * 64 + mi * 16 + lh * 4 + j;
                if (row < mcnt) {
                    int col = n0 + wc * 64 + ni * 16 + lr;
                    atomicAdd(&out[(size_t)toks[row] * HID + col],
                              rws[row] * acc[mi][ni][j]);
                }
            }
}

extern "C" void kernel_launch(void* const* d_in, const int* in_sizes, int n_in,
                              void* d_out, int out_size, void* d_ws, size_t ws_size,
                              hipStream_t stream) {
    const float* x       = (const float*)d_in[0];  // [2,1024,2048]
    const float* gate_w  = (const float*)d_in[1];  // [8,2048]
    const float* w_gate  = (const float*)d_in[2];  // [8,2048,768]
    const float* w_up    = (const float*)d_in[3];  // [8,2048,768]
    const float* w_down  = (const float*)d_in[4];  // [8,768,2048]
    float* out = (float*)d_out;                    // 2048*2048 out + 2048*8 logits

    char* ws = (char*)d_ws;
    int*   topk_idx  = (int*)  (ws + 0);
    float* topk_w    = (float*)(ws + 16384);
    int*   counts    = (int*)  (ws + 32768);
    int*   offsets   = (int*)  (ws + 32800);
    int*   row_token = (int*)  (ws + 33024);
    float* row_w     = (float*)(ws + 49408);
    int*   elist_t   = (int*)  (ws + 65792);
    float* elist_w   = (float*)(ws + 131328);

    unsigned short* xb   = (unsigned short*)(ws + 196864);
    unsigned short* wg_t = (unsigned short*)(ws + 8585472);
    unsigned short* wu_t = (unsigned short*)(ws + 33751296);
    unsigned short* wd_t = (unsigned short*)(ws + 58917120);
    unsigned short* hb   = (unsigned short*)(ws + 84082944);

    float* logits_out = out + (size_t)NTOK * HID;

    k1_all<<<512 + 2304, 256, 0, stream>>>(
        x, gate_w, w_gate, w_up, w_down, out, logits_out,
        topk_idx, topk_w, xb, wg_t, wu_t, wd_t);
    moe_build_kernel<<<1, 1024, 0, stream>>>(topk_idx, topk_w, counts, offsets,
                                             elist_t, elist_w, row_token, row_w);
    dim3 gridA(NEXP, NTOK / 64, FINT / 64);
    moe_stage_a_mfma<<<gridA, 256, 0, stream>>>(xb, wg_t, wu_t, counts, offsets,
                                                row_token, hb);
    dim3 gridB(NEXP, NTOK / 128, HID / 128);
    moe_stage_b_mfma<<<gridB, 256, 0, stream>>>(hb, wd_t, counts, offsets,
                                                row_token, row_w, out);
}

// Round 15
// 149.602 us; speedup vs baseline: 1.1837x; 1.1837x over previous
//
#include <hip/hip_runtime.h>
#include <hip/hip_bf16.h>
#include <math.h>

#define NTOK 2048
#define HID 2048
#define NEXP 8
#define FINT 768
#define TOPK 2

typedef __attribute__((ext_vector_type(8))) short bf16x8;
typedef __attribute__((ext_vector_type(4))) float f32x4;

static __device__ __forceinline__ unsigned short f2bf(float f) {
    union { float f; unsigned u; } v; v.f = f;
    unsigned r = v.u + 0x7fffu + ((v.u >> 16) & 1u);
    return (unsigned short)(r >> 16);
}

static __device__ __forceinline__ void gl16(const void* g, void* l) {
    __builtin_amdgcn_global_load_lds(
        (const __attribute__((address_space(1))) unsigned int*)g,
        (__attribute__((address_space(3))) unsigned int*)(uintptr_t)l,
        16, 0, 0);
}

// ---------------- workspace layout (bytes) ----------------
// 0       : topk_idx  int[4096]
// 16384   : topk_w    f32[4096]
// 32768   : counts    int[8]
// 32800   : offsets   int[8]
// 33024   : row_token int[4096]
// 49408   : row_w     f32[4096]
// 65792   : elist_t   int[8*2048]
// 131328  : elist_w   f32[8*2048]
// 196864  : x_bf16    [2048][2048]        8388608
// 8585472 : wg_t      [8][768][2048] bf16 25165824
// 33751296: wu_t      [8][768][2048] bf16 25165824
// 58917120: wd_t      [8][2048][768] bf16 25165824
// 84082944: h_buf     [4224][768]    bf16 6488064   -> end 90571008

struct TP { const float* s; unsigned short* d; int R, C, r0, c0; };

static __device__ __forceinline__ TP tp_decode(
        int t,
        const float* wg, const float* wu, const float* wd,
        unsigned short* wgt, unsigned short* wut, unsigned short* wdt) {
    TP p;
    if (t < 6144) {
        int e = t / 768, sub = t % 768;
        if (sub < 384) { p.s = wg; p.d = wgt; }
        else           { p.s = wu; p.d = wut; sub -= 384; }
        p.R = HID; p.C = FINT;
        p.r0 = (sub / 12) * 64; p.c0 = (sub % 12) * 64;   // [2048][768]: 32x12
        p.s += (size_t)e * HID * FINT; p.d += (size_t)e * HID * FINT;
    } else {
        t -= 6144;
        int e = t / 384, sub = t % 384;
        p.s = wd + (size_t)e * FINT * HID; p.d = wdt + (size_t)e * FINT * HID;
        p.R = FINT; p.C = HID;
        p.r0 = (sub / 32) * 64; p.c0 = (sub % 32) * 64;   // [768][2048]: 12x32
    }
    return p;
}

// r12 tile body, verbatim: 64x64, XOR-swizzled f32 LDS, vectorized both phases.
static __device__ __forceinline__ void transpose_tile(
        const TP& p, float* tile, int tid) {
    {
        int rbase = tid >> 4;           // 0..15
        int ch = tid & 15;              // source 16B chunk (4 floats)
        #pragma unroll
        for (int i = 0; i < 4; ++i) {
            int row = i * 16 + rbase;
            float4 v = *(const float4*)&p.s[(size_t)(p.r0 + row) * p.C + p.c0 + ch * 4];
            int q = ch ^ (row & 15);    // swizzled chunk
            *(float4*)&tile[row * 64 + q * 4] = v;
        }
    }
    __syncthreads();
    {
        int r16 = (tid & 15) * 4;       // 4 tile rows
        int cg = tid >> 4;              // 4-col group 0..15
        float4 v[4];
        #pragma unroll
        for (int j = 0; j < 4; ++j) {
            int row = r16 + j;
            int q = cg ^ (row & 15);
            v[j] = *(const float4*)&tile[row * 64 + q * 4];
        }
        #pragma unroll
        for (int i = 0; i < 4; ++i) {
            float c0v = (i == 0) ? v[0].x : (i == 1) ? v[0].y : (i == 2) ? v[0].z : v[0].w;
            float c1v = (i == 0) ? v[1].x : (i == 1) ? v[1].y : (i == 2) ? v[1].z : v[1].w;
            float c2v = (i == 0) ? v[2].x : (i == 1) ? v[2].y : (i == 2) ? v[2].z : v[2].w;
            float c3v = (i == 0) ? v[3].x : (i == 1) ? v[3].y : (i == 2) ? v[3].z : v[3].w;
            ushort4 o = make_ushort4(f2bf(c0v), f2bf(c1v), f2bf(c2v), f2bf(c3v));
            *(uint2*)&p.d[(size_t)(p.c0 + cg * 4 + i) * p.R + p.r0 + r16] = *(const uint2*)&o;
        }
    }
}

// ---------------- K1: router + x-cvt + out-zero  UNION  transposes ----------
// blocks [0,512): router (4 tokens each; zeroes out rows; writes xb)
// blocks [512, 2816): 4 FAR-STRIDED 64x64 transpose tiles each (t, t+2304, ...)
//   -> 4x fewer blocks (amortize block setup/drain), per-tile write pattern
//      identical to r12's distribution (controls r14's WRITE_SIZE failure).
__global__ __launch_bounds__(256) void k1_all(
        const float* __restrict__ x,
        const float* __restrict__ gw,
        const float* __restrict__ wg, const float* __restrict__ wu,
        const float* __restrict__ wd,
        float* __restrict__ out,
        float* __restrict__ logits_out,
        int* __restrict__ topk_idx,
        float* __restrict__ topk_w,
        unsigned short* __restrict__ xb,
        unsigned short* __restrict__ wgt, unsigned short* __restrict__ wut,
        unsigned short* __restrict__ wdt) {
    __shared__ __align__(16) float tile[64 * 64];   // 16 KB
    int bid = blockIdx.x;
    if (bid < 512) {
        int w = threadIdx.x >> 6, l = threadIdx.x & 63;
        int t = bid * 4 + w;
        const float4* xr = (const float4*)(x + (size_t)t * HID);
        unsigned short* xbr = xb + (size_t)t * HID;
        float4 v[8];
        #pragma unroll
        for (int i = 0; i < 8; ++i) v[i] = xr[i * 64 + l];
        #pragma unroll
        for (int i = 0; i < 8; ++i)
            *(ushort4*)&xbr[(i * 64 + l) * 4] =
                make_ushort4(f2bf(v[i].x), f2bf(v[i].y), f2bf(v[i].z), f2bf(v[i].w));
        {
            float4 z = make_float4(0.f, 0.f, 0.f, 0.f);
            float4* orow = (float4*)(out + (size_t)t * HID);
            #pragma unroll
            for (int i = 0; i < 8; ++i) orow[i * 64 + l] = z;
        }
        float acc[NEXP];
        #pragma unroll
        for (int e = 0; e < NEXP; ++e) {
            const float4* gr = (const float4*)(gw + (size_t)e * HID);
            float a = 0.f;
            #pragma unroll
            for (int i = 0; i < 8; ++i) {
                float4 g = gr[i * 64 + l];
                a += v[i].x * g.x + v[i].y * g.y + v[i].z * g.z + v[i].w * g.w;
            }
            acc[e] = a;
        }
        #pragma unroll
        for (int off = 32; off > 0; off >>= 1)
            #pragma unroll
            for (int e = 0; e < NEXP; ++e) acc[e] += __shfl_xor(acc[e], off);
        if (l == 0) {
            float m = -1e30f;
            #pragma unroll
            for (int i = 0; i < NEXP; ++i) m = fmaxf(m, acc[i]);
            float p[NEXP];
            #pragma unroll
            for (int i = 0; i < NEXP; ++i) p[i] = expf(acc[i] - m);
            int i0 = 0;
            #pragma unroll
            for (int i = 1; i < NEXP; ++i) if (p[i] > p[i0]) i0 = i;
            int i1 = (i0 == 0) ? 1 : 0;
            #pragma unroll
            for (int i = 0; i < NEXP; ++i) if (i != i0 && p[i] > p[i1]) i1 = i;
            float w0 = p[i0], w1 = p[i1], sw = w0 + w1;
            topk_idx[t * 2 + 0] = i0;
            topk_idx[t * 2 + 1] = i1;
            topk_w[t * 2 + 0] = w0 / sw;
            topk_w[t * 2 + 1] = w1 / sw;
            #pragma unroll
            for (int i = 0; i < NEXP; ++i) logits_out[(size_t)t * NEXP + i] = acc[i];
        }
    } else {
        int b = bid - 512;              // 0..2303
        int tid = threadIdx.x;
        #pragma unroll
        for (int it = 0; it < 4; ++it) {
            TP p = tp_decode(b + it * 2304, wg, wu, wd, wgt, wut, wdt);
            transpose_tile(p, tile, tid);
            __syncthreads();            // guard tile reuse
        }
    }
}

__global__ void moe_build_kernel(const int* __restrict__ topk_idx,
                                 const float* __restrict__ topk_w,
                                 int* __restrict__ counts,
                                 int* __restrict__ offsets,
                                 int* __restrict__ elist_t,
                                 float* __restrict__ elist_w,
                                 int* __restrict__ row_token,
                                 float* __restrict__ row_w) {
    __shared__ int scnt[NEXP];
    __shared__ int soff[NEXP];
    int tid = threadIdx.x; // 1024
    if (tid < NEXP) scnt[tid] = 0;
    __syncthreads();
    for (int t = tid; t < NTOK; t += 1024) {
        #pragma unroll
        for (int k = 0; k < TOPK; ++k) {
            int e = topk_idx[t * 2 + k];
            float w = topk_w[t * 2 + k];
            int slot = atomicAdd(&scnt[e], 1);
            elist_t[e * NTOK + slot] = t;
            elist_w[e * NTOK + slot] = w;
        }
    }
    __syncthreads();
    if (tid == 0) {
        int o = 0;
        for (int e = 0; e < NEXP; ++e) {
            soff[e] = o; offsets[e] = o; counts[e] = scnt[e]; o += scnt[e];
        }
    }
    __syncthreads();
    for (int e = 0; e < NEXP; ++e) {
        int c = scnt[e], o = soff[e];
        for (int s = tid; s < c; s += 1024) {
            row_token[o + s] = elist_t[e * NTOK + s];
            row_w[o + s]     = elist_w[e * NTOK + s];
        }
    }
}

// ---------------- MFMA stage A: h = silu(x*Wg) * (x*Wu) ----------------
// 64x64 tile (g+u share A), BK=64, 4 waves 2x2, double-buffered prefetch.
__global__ __launch_bounds__(256) void moe_stage_a_mfma(
        const unsigned short* __restrict__ xb,    // [2048][2048]
        const unsigned short* __restrict__ wgt,   // [8][768][2048]
        const unsigned short* __restrict__ wut,   // [8][768][2048]
        const int* __restrict__ counts,
        const int* __restrict__ offsets,
        const int* __restrict__ row_token,
        unsigned short* __restrict__ h_buf) {     // [4224][768]
    int e = blockIdx.x, mt = blockIdx.y, nt = blockIdx.z;
    int count = counts[e];
    int m0 = mt * 64;
    if (m0 >= count) return;
    int off = offsets[e];
    int n0 = nt * 64;
    int mcnt = min(64, count - m0);
    int tid = threadIdx.x;

    __shared__ __align__(16) unsigned short As[2][64 * 64];
    __shared__ __align__(16) unsigned short Bg[2][64 * 64];
    __shared__ __align__(16) unsigned short Bu[2][64 * 64];
    __shared__ int toks[64];
    if (tid < 64) toks[tid] = row_token[off + m0 + min(tid, mcnt - 1)];
    __syncthreads();

    int w = tid >> 6, l = tid & 63;
    int wr = w >> 1, wc = w & 1;
    int lr = l & 15, lh = l >> 4;
    int rA = w * 8 + (l >> 3);    // staging row (0..31), +32 per issue
    int cA = l & 7;               // 16B chunk within 128B row

    const unsigned short* wgE = wgt + (size_t)e * FINT * HID + (size_t)n0 * HID;
    const unsigned short* wuE = wut + (size_t)e * FINT * HID + (size_t)n0 * HID;

    f32x4 gacc[2][2] = {};
    f32x4 uacc[2][2] = {};

    auto STAGE = [&](int buf, int k0) {
        #pragma unroll
        for (int i = 0; i < 2; ++i) {
            int row = 32 * i + rA;
            int sc = (cA ^ (row & 7)) << 3;      // pre-swizzled source offset
            size_t db = (size_t)(32 * i + w * 8) * 128;
            gl16(xb + (size_t)toks[row] * HID + k0 + sc, (char*)&As[buf][0] + db);
            gl16(wgE + (size_t)row * HID + k0 + sc,      (char*)&Bg[buf][0] + db);
            gl16(wuE + (size_t)row * HID + k0 + sc,      (char*)&Bu[buf][0] + db);
        }
    };

    auto COMPUTE = [&](int buf) {
        #pragma unroll
        for (int ks = 0; ks < 2; ++ks) {
            bf16x8 af[2], bg[2], bu[2];
            #pragma unroll
            for (int mi = 0; mi < 2; ++mi) {
                int row = wr * 32 + mi * 16 + lr;
                int byte = row * 128 + ((ks * 64 + lh * 16) ^ ((row & 7) << 4));
                af[mi] = *(const bf16x8*)((const char*)&As[buf][0] + byte);
            }
            #pragma unroll
            for (int ni = 0; ni < 2; ++ni) {
                int row = wc * 32 + ni * 16 + lr;
                int byte = row * 128 + ((ks * 64 + lh * 16) ^ ((row & 7) << 4));
                bg[ni] = *(const bf16x8*)((const char*)&Bg[buf][0] + byte);
                bu[ni] = *(const bf16x8*)((const char*)&Bu[buf][0] + byte);
            }
            #pragma unroll
            for (int mi = 0; mi < 2; ++mi)
                #pragma unroll
                for (int ni = 0; ni < 2; ++ni) {
                    gacc[mi][ni] = __builtin_amdgcn_mfma_f32_16x16x32_bf16(af[mi], bg[ni], gacc[mi][ni], 0, 0, 0);
                    uacc[mi][ni] = __builtin_amdgcn_mfma_f32_16x16x32_bf16(af[mi], bu[ni], uacc[mi][ni], 0, 0, 0);
                }
        }
    };

    STAGE(0, 0);
    __syncthreads();                   // drain buf0
    for (int t = 0; t < HID / 64; ++t) {
        int cur = t & 1;
        if (t + 1 < HID / 64) STAGE(cur ^ 1, (t + 1) * 64);  // prefetch next
        COMPUTE(cur);                  // overlap with in-flight loads
        __syncthreads();               // drain next-tile loads + guard reuse
    }

    #pragma unroll
    for (int mi = 0; mi < 2; ++mi)
        #pragma unroll
        for (int ni = 0; ni < 2; ++ni)
            #pragma unroll
            for (int j = 0; j < 4; ++j) {
                int row = wr * 32 + mi * 16 + lh * 4 + j;
                if (row < mcnt) {
                    int col = wc * 32 + ni * 16 + lr;
                    float g = gacc[mi][ni][j], u = uacc[mi][ni][j];
                    float hv = g / (1.f + expf(-g)) * u;
                    h_buf[(size_t)(off + m0 + row) * FINT + n0 + col] = f2bf(hv);
                }
            }
}

// ---------------- MFMA stage B: out[tok] += w * (h * Wd) ----------------
__global__ __launch_bounds__(256) void moe_stage_b_mfma(
        const unsigned short* __restrict__ h_buf, // [4224][768]
        const unsigned short* __restrict__ wdt,   // [8][2048][768]
        const int* __restrict__ counts,
        const int* __restrict__ offsets,
        const int* __restrict__ row_token,
        const float* __restrict__ row_w,
        float* __restrict__ out) {
    int e = blockIdx.x, mt = blockIdx.y, nt = blockIdx.z;
    int count = counts[e];
    int m0 = mt * 128;
    if (m0 >= count) return;
    int off = offsets[e];
    int n0 = nt * 128;
    int mcnt = min(128, count - m0);
    int tid = threadIdx.x;

    __shared__ __align__(16) unsigned short As[2][128 * 64];  // 32 KB
    __shared__ __align__(16) unsigned short Bs[2][128 * 64];  // 32 KB
    __shared__ int toks[128];
    __shared__ float rws[128];
    if (tid < 128) {
        int mm = min(tid, mcnt - 1);
        toks[tid] = row_token[off + m0 + mm];
        rws[tid] = row_w[off + m0 + mm];
    }
    __syncthreads();

    int w = tid >> 6, l = tid & 63;
    int wr = w >> 1, wc = w & 1;
    int lr = l & 15, lh = l >> 4;
    int wbase = (tid & 192) * 16;   // wave-uniform byte base within 4KB slab

    const unsigned short* hb = h_buf + (size_t)(off + m0) * FINT;
    const unsigned short* wdE = wdt + (size_t)e * HID * FINT + (size_t)n0 * FINT;

    f32x4 acc[4][4] = {};

    auto STAGE = [&](int buf, int k0) {
        #pragma unroll
        for (int i = 0; i < 4; ++i) {
            int s = i * 256 + tid;
            int row = s >> 3, c = s & 7;
            int sc = (c ^ (row & 7)) << 3;
            gl16(hb + (size_t)row * FINT + k0 + sc,  (char*)&As[buf][0] + i * 4096 + wbase);
            gl16(wdE + (size_t)row * FINT + k0 + sc, (char*)&Bs[buf][0] + i * 4096 + wbase);
        }
    };

    auto COMPUTE = [&](int buf) {
        #pragma unroll
        for (int ks = 0; ks < 2; ++ks) {
            bf16x8 af[4], bf[4];
            #pragma unroll
            for (int mi = 0; mi < 4; ++mi) {
                int row = wr * 64 + mi * 16 + lr;
                int byte = row * 128 + ((ks * 64 + lh * 16) ^ ((row & 7) << 4));
                af[mi] = *(const bf16x8*)((const char*)&As[buf][0] + byte);
            }
            #pragma unroll
            for (int ni = 0; ni < 4; ++ni) {
                int row = wc * 64 + ni * 16 + lr;
                int byte = row * 128 + ((ks * 64 + lh * 16) ^ ((row & 7) << 4));
                bf[ni] = *(const bf16x8*)((const char*)&Bs[buf][0] + byte);
            }
            #pragma unroll
            for (int mi = 0; mi < 4; ++mi)
                #pragma unroll
                for (int ni = 0; ni < 4; ++ni)
                    acc[mi][ni] = __builtin_amdgcn_mfma_f32_16x16x32_bf16(af[mi], bf[ni], acc[mi][ni], 0, 0, 0);
        }
    };

    STAGE(0, 0);
    __syncthreads();
    for (int t = 0; t < FINT / 64; ++t) {
        int cur = t & 1;
        if (t + 1 < FINT / 64) STAGE(cur ^ 1, (t + 1) * 64);
        COMPUTE(cur);
        __syncthreads();
    }

    #pragma unroll
    for (int mi = 0; mi < 4; ++mi)
        #pragma unroll
        for (int ni = 0; ni < 4; ++ni)
            #pragma unroll
            for (int j = 0; j < 4; ++j) {
                int row = wr * 64 + mi * 16 + lh * 4 + j;
                if (row < mcnt) {
                    int col = n0 + wc * 64 + ni * 16 + lr;
                    atomicAdd(&out[(size_t)toks[row] * HID + col],
                              rws[row] * acc[mi][ni][j]);
                }
            }
}

extern "C" void kernel_launch(void* const* d_in, const int* in_sizes, int n_in,
                              void* d_out, int out_size, void* d_ws, size_t ws_size,
                              hipStream_t stream) {
    const float* x       = (const float*)d_in[0];  // [2,1024,2048]
    const float* gate_w  = (const float*)d_in[1];  // [8,2048]
    const float* w_gate  = (const float*)d_in[2];  // [8,2048,768]
    const float* w_up    = (const float*)d_in[3];  // [8,2048,768]
    const float* w_down  = (const float*)d_in[4];  // [8,768,2048]
    float* out = (float*)d_out;                    // 2048*2048 out + 2048*8 logits

    char* ws = (char*)d_ws;
    int*   topk_idx  = (int*)  (ws + 0);
    float* topk_w    = (float*)(ws + 16384);
    int*   counts    = (int*)  (ws + 32768);
    int*   offsets   = (int*)  (ws + 32800);
    int*   row_token = (int*)  (ws + 33024);
    float* row_w     = (float*)(ws + 49408);
    int*   elist_t   = (int*)  (ws + 65792);
    float* elist_w   = (float*)(ws + 131328);

    unsigned short* xb   = (unsigned short*)(ws + 196864);
    unsigned short* wg_t = (unsigned short*)(ws + 8585472);
    unsigned short* wu_t = (unsigned short*)(ws + 33751296);
    unsigned short* wd_t = (unsigned short*)(ws + 58917120);
    unsigned short* hb   = (unsigned short*)(ws + 84082944);

    float* logits_out = out + (size_t)NTOK * HID;

    k1_all<<<512 + 2304, 256, 0, stream>>>(
        x, gate_w, w_gate, w_up, w_down, out, logits_out,
        topk_idx, topk_w, xb, wg_t, wu_t, wd_t);
    moe_build_kernel<<<1, 1024, 0, stream>>>(topk_idx, topk_w, counts, offsets,
                                             elist_t, elist_w, row_token, row_w);
    dim3 gridA(NEXP, NTOK / 64, FINT / 64);
    moe_stage_a_mfma<<<gridA, 256, 0, stream>>>(xb, wg_t, wu_t, counts, offsets,
                                                row_token, hb);
    dim3 gridB(NEXP, NTOK / 128, HID / 128);
    moe_stage_b_mfma<<<gridB, 256, 0, stream>>>(hb, wd_t, counts, offsets,
                                                row_token, row_w, out);
}